// Round 12
// baseline (844.635 us; speedup 1.0000x reference)
//
#include <hip/hip_runtime.h>

#define N_NODES 50000
#define E_EDGES 262144

typedef __attribute__((ext_vector_type(8))) short bf16x8;
typedef __attribute__((ext_vector_type(4))) float f32x4;

union V16 { uint4 u; bf16x8 h; };

__device__ __forceinline__ unsigned rne_pack(float a, float b) {
  unsigned ua = __float_as_uint(a); ua += 0x7fffu + ((ua >> 16) & 1u);
  unsigned ub = __float_as_uint(b); ub += 0x7fffu + ((ub >> 16) & 1u);
  return (ua >> 16) | (ub & 0xffff0000u);
}
__device__ __forceinline__ float bflo(unsigned u) { return __uint_as_float(u << 16); }
__device__ __forceinline__ float bfhi(unsigned u) { return __uint_as_float(u & 0xffff0000u); }
// (bits(a)>>16) | (bits(b)&0xffff0000) in one v_perm_b32
__device__ __forceinline__ unsigned perm_pack(float a, float b) {
  return __builtin_amdgcn_perm(__float_as_uint(b), __float_as_uint(a), 0x07060302u);
}

// ---- prep: node_repr fp32 -> bf16 (RNE) ----
__global__ void cvt_node_kernel(const float* __restrict__ x, unsigned short* __restrict__ y) {
  int i = (blockIdx.x * 256 + threadIdx.x) * 8;
  float4 f0 = *(const float4*)(x + i);
  float4 f1 = *(const float4*)(x + i + 4);
  uint4 o;
  o.x = rne_pack(f0.x, f0.y);
  o.y = rne_pack(f0.z, f0.w);
  o.z = rne_pack(f1.x, f1.y);
  o.w = rne_pack(f1.z, f1.w);
  *(uint4*)(y + i) = o;
}

// ---- prep: W1 (1024x512 row-major in->out) -> W1pp2 bf16, 16-B units laid out
// [step(8)][sq=s*4+quad(16)][col(512)], unit = W1[k0..k0+8)[col], k0=s*256+step*32+quad*8
__global__ void prep_w1pp2_kernel(const float* __restrict__ w1, unsigned short* __restrict__ w1pp2) {
  int t = blockIdx.x * 256 + threadIdx.x;  // 65536 units
  int step = t >> 13;
  int rem = t & 8191;
  int sq = rem >> 9;
  int col = rem & 511;
  int s = sq >> 2, qd = sq & 3;
  int k0 = s * 256 + step * 32 + qd * 8;
  float f[8];
#pragma unroll
  for (int i = 0; i < 8; ++i) f[i] = w1[(size_t)(k0 + i) * 512 + col];
  uint4 o;
  o.x = rne_pack(f[0], f[1]);
  o.y = rne_pack(f[2], f[3]);
  o.z = rne_pack(f[4], f[5]);
  o.w = rne_pack(f[6], f[7]);
  *(uint4*)(w1pp2 + (size_t)t * 8) = o;
}

// ---- prep: out[e][c] = b2[c] ----
__global__ void init_out_kernel(float* __restrict__ out, const float* __restrict__ b2) {
  int i = blockIdx.x * 256 + threadIdx.x;
  float2 v; v.x = b2[0]; v.y = b2[1];
  *(float2*)(out + (size_t)i * 2) = v;
}

// ---- main fused kernel: 512 thr = 8 waves, m-split (wave = 16 edges x 64 cols).
//      NO LDS, NO barriers. A register-gather prefetched 1 step; B streamed (L1-shared
//      across all 8 waves); builds deduped by construction (each wave owns its edges) ----
__global__ __launch_bounds__(512) void edge_mlp_kernel(
    const unsigned short* __restrict__ nodeb,  // [50000][256] bf16
    const unsigned short* __restrict__ w1pp2,  // repacked W1 (see prep)
    const int* __restrict__ src,
    const int* __restrict__ dst,
    const float* __restrict__ b1,
    const float* __restrict__ w2,   // [512][2] fp32
    float* __restrict__ out) {      // [E][2] fp32, pre-init with b2
  const int tid = threadIdx.x;
  const int wid = tid >> 6;        // 0..7
  const int lane = tid & 63;
  const int quad = lane >> 4;
  const int l16 = lane & 15;
  const int bx = blockIdx.x;
  // XCD swizzle: the 8 n-siblings of one m-tile land on one XCD (A-row L2 reuse)
  const int xc = bx & 7;
  const int n_idx = (bx >> 3) & 7;           // 0..7 (64-col slices)
  const int m_idx = (bx >> 6) * 8 + xc;      // 0..2047 (128-edge tiles)
  const int row0 = m_idx * 128;
  const int erow = row0 + wid * 16 + l16;    // this lane's edge
  const int n0 = n_idx * 64;

  const char* nodeB = (const char*)nodeb;
  const char* w1B = (const char*)w1pp2;

  // A lane pointers: row base + quad*16; per-step +step*64 folds into the load imm
  const char* pi = nodeB + ((unsigned)src[erow] << 9) + (unsigned)(quad << 4);
  const char* pj = nodeB + ((unsigned)dst[erow] << 9) + (unsigned)(quad << 4);

  // B offsets: (s*4+quad)*8192 + (n0+l16)*16 (+ step*131072 via w1s, nt*256 via imm)
  unsigned bOff[4];
#pragma unroll
  for (int s = 0; s < 4; ++s)
    bOff[s] = (unsigned)((s * 4 + quad) * 8192 + (n0 + l16) * 16);
  const char* w1s = w1B;

  f32x4 acc[4];
#pragma unroll
  for (int nt = 0; nt < 4; ++nt) acc[nt] = (f32x4){0.f, 0.f, 0.f, 0.f};

  // prologue: A(0)
  V16 hiC, hjC;
  hiC.u = *(const uint4*)pi;
  hjC.u = *(const uint4*)pj;

#pragma unroll 2
  for (int step = 0; step < 8; ++step) {
    // 1) B(t) loads — FIFO head, L1-resident (all 8 waves read the same 16 KB tile)
    V16 bf[4][4];
#pragma unroll
    for (int s = 0; s < 4; ++s)
#pragma unroll
      for (int nt = 0; nt < 4; ++nt)
        bf[s][nt].u = *(const uint4*)(w1s + bOff[s] + nt * 256);
    // 2) A(t+1) prefetch — FIFO tail, consumed next iteration
    V16 hiN, hjN;
    if (step < 7) {
      hiN.u = *(const uint4*)(pi + (step + 1) * 64);
      hjN.u = *(const uint4*)(pj + (step + 1) * 64);
    }
    // 3) MFMA s=0 (hi), s=1 (hj)
#pragma unroll
    for (int nt = 0; nt < 4; ++nt)
      acc[nt] = __builtin_amdgcn_mfma_f32_16x16x32_bf16(hiC.h, bf[0][nt].h, acc[nt], 0, 0, 0);
#pragma unroll
    for (int nt = 0; nt < 4; ++nt)
      acc[nt] = __builtin_amdgcn_mfma_f32_16x16x32_bf16(hjC.h, bf[1][nt].h, acc[nt], 0, 0, 0);
    // 4) build a2/a3 (ONCE — this wave owns these edges); float2 ops -> v_pk_*_f32
    {
      const unsigned hw[4] = {hiC.u.x, hiC.u.y, hiC.u.z, hiC.u.w};
      const unsigned jw[4] = {hjC.u.x, hjC.u.y, hjC.u.z, hjC.u.w};
      unsigned d[4], pr[4];
#pragma unroll
      for (int w = 0; w < 4; ++w) {
        float2 iv = make_float2(bflo(hw[w]), bfhi(hw[w]));
        float2 jv = make_float2(bflo(jw[w]), bfhi(jw[w]));
        float2 dv = make_float2(iv.x - jv.x, iv.y - jv.y);
        float2 pv = make_float2(iv.x * jv.x, iv.y * jv.y);
        d[w] = perm_pack(dv.x, dv.y) & 0x7fff7fffu;
        pr[w] = perm_pack(pv.x, pv.y);
      }
      V16 a2, a3;
      a2.u = make_uint4(d[0], d[1], d[2], d[3]);
      a3.u = make_uint4(pr[0], pr[1], pr[2], pr[3]);
#pragma unroll
      for (int nt = 0; nt < 4; ++nt)
        acc[nt] = __builtin_amdgcn_mfma_f32_16x16x32_bf16(a2.h, bf[2][nt].h, acc[nt], 0, 0, 0);
#pragma unroll
      for (int nt = 0; nt < 4; ++nt)
        acc[nt] = __builtin_amdgcn_mfma_f32_16x16x32_bf16(a3.h, bf[3][nt].h, acc[nt], 0, 0, 0);
    }
    hiC = hiN;
    hjC = hjN;
    w1s += 131072;
  }

  // ---- epilogue: bias + ReLU + W2, 16-lane shuffle reduce, atomic out ----
  {
    float pc0[4] = {0.f, 0.f, 0.f, 0.f};
    float pc1[4] = {0.f, 0.f, 0.f, 0.f};
#pragma unroll
    for (int nt = 0; nt < 4; ++nt) {
      int gc = n0 + nt * 16 + l16;
      float b1v = b1[gc];
      float w20 = w2[gc * 2 + 0];
      float w21 = w2[gc * 2 + 1];
#pragma unroll
      for (int r = 0; r < 4; ++r) {
        float v = fmaxf(acc[nt][r] + b1v, 0.f);
        pc0[r] = fmaf(v, w20, pc0[r]);
        pc1[r] = fmaf(v, w21, pc1[r]);
      }
    }
#pragma unroll
    for (int r = 0; r < 4; ++r) {
      float s0 = pc0[r], s1 = pc1[r];
#pragma unroll
      for (int off = 1; off < 16; off <<= 1) {
        s0 += __shfl_xor(s0, off);
        s1 += __shfl_xor(s1, off);
      }
      int e = row0 + wid * 16 + quad * 4 + r;  // C/D: row = quad*4 + r
      if (l16 == 0) unsafeAtomicAdd(&out[(size_t)e * 2 + 0], s0);
      if (l16 == 1) unsafeAtomicAdd(&out[(size_t)e * 2 + 1], s1);
    }
  }
}

extern "C" void kernel_launch(void* const* d_in, const int* in_sizes, int n_in,
                              void* d_out, int out_size, void* d_ws, size_t ws_size,
                              hipStream_t stream) {
  const float* node = (const float*)d_in[0];
  const int* src = (const int*)d_in[1];
  const int* dst = (const int*)d_in[2];
  const float* W1 = (const float*)d_in[3];
  const float* b1 = (const float*)d_in[4];
  const float* W2 = (const float*)d_in[5];
  const float* b2 = (const float*)d_in[6];
  float* out = (float*)d_out;

  unsigned short* nodeb = (unsigned short*)d_ws;                      // 25,600,000 B
  unsigned short* w1pp2 = (unsigned short*)((char*)d_ws + 25600000);  // 1,048,576 B

  cvt_node_kernel<<<6250, 256, 0, stream>>>(node, nodeb);
  prep_w1pp2_kernel<<<256, 256, 0, stream>>>(W1, w1pp2);
  init_out_kernel<<<1024, 256, 0, stream>>>(out, b2);
  // 2048 m-tiles (128 edges) x 8 n-slices (64 cols)
  edge_mlp_kernel<<<16384, 512, 0, stream>>>(nodeb, w1pp2, src, dst, b1, W2, out);
}

// Round 13
// 493.128 us; speedup vs baseline: 1.7128x; 1.7128x over previous
//
#include <hip/hip_runtime.h>

#define N_NODES 50000
#define E_EDGES 262144

typedef __attribute__((ext_vector_type(8))) short bf16x8;
typedef __attribute__((ext_vector_type(4))) float f32x4;

union V16 { uint4 u; bf16x8 h; };

__device__ __forceinline__ unsigned rne_pack(float a, float b) {
  unsigned ua = __float_as_uint(a); ua += 0x7fffu + ((ua >> 16) & 1u);
  unsigned ub = __float_as_uint(b); ub += 0x7fffu + ((ub >> 16) & 1u);
  return (ua >> 16) | (ub & 0xffff0000u);
}
__device__ __forceinline__ float bflo(unsigned u) { return __uint_as_float(u << 16); }
__device__ __forceinline__ float bfhi(unsigned u) { return __uint_as_float(u & 0xffff0000u); }
// (bits(a)>>16) | (bits(b)&0xffff0000) in one v_perm_b32
__device__ __forceinline__ unsigned perm_pack(float a, float b) {
  return __builtin_amdgcn_perm(__float_as_uint(b), __float_as_uint(a), 0x07060302u);
}
__device__ __forceinline__ void async_gather16(const void* gptr, void* lptr) {
  __builtin_amdgcn_global_load_lds(
      (const __attribute__((address_space(1))) void*)gptr,
      (__attribute__((address_space(3))) void*)lptr, 16, 0, 0);
}

// ---- prep: node_repr fp32 -> bf16 (RNE) ----
__global__ void cvt_node_kernel(const float* __restrict__ x, unsigned short* __restrict__ y) {
  int i = (blockIdx.x * 256 + threadIdx.x) * 8;
  float4 f0 = *(const float4*)(x + i);
  float4 f1 = *(const float4*)(x + i + 4);
  uint4 o;
  o.x = rne_pack(f0.x, f0.y);
  o.y = rne_pack(f0.z, f0.w);
  o.z = rne_pack(f1.x, f1.y);
  o.w = rne_pack(f1.z, f1.w);
  *(uint4*)(y + i) = o;
}

// ---- prep: W1 (1024x512 row-major in->out) -> W1pp2 bf16, 16-B units laid out
// [step(8)][sq=s*4+quad(16)][col(512)], unit = W1[k0..k0+8)[col], k0=s*256+step*32+quad*8
__global__ void prep_w1pp2_kernel(const float* __restrict__ w1, unsigned short* __restrict__ w1pp2) {
  int t = blockIdx.x * 256 + threadIdx.x;  // 65536 units
  int step = t >> 13;
  int rem = t & 8191;
  int sq = rem >> 9;
  int col = rem & 511;
  int s = sq >> 2, qd = sq & 3;
  int k0 = s * 256 + step * 32 + qd * 8;
  float f[8];
#pragma unroll
  for (int i = 0; i < 8; ++i) f[i] = w1[(size_t)(k0 + i) * 512 + col];
  uint4 o;
  o.x = rne_pack(f[0], f[1]);
  o.y = rne_pack(f[2], f[3]);
  o.z = rne_pack(f[4], f[5]);
  o.w = rne_pack(f[6], f[7]);
  *(uint4*)(w1pp2 + (size_t)t * 8) = o;
}

// ---- prep: out[e][c] = b2[c] ----
__global__ void init_out_kernel(float* __restrict__ out, const float* __restrict__ b2) {
  int i = blockIdx.x * 256 + threadIdx.x;
  float2 v; v.x = b2[0]; v.y = b2[1];
  *(float2*)(out + (size_t)i * 2) = v;
}

// ---- main fused kernel: 512 thr = 8 waves; block tile 64 edges x 256 cols;
//      wave = 64 edges x 32 cols (acc[4][2] = 32 AGPR -> 4 waves/SIMD with (512,4)).
//      All of A staged once in 64KB LDS, ONE barrier, barrier-free K-loop ----
__global__ __launch_bounds__(512, 4) void edge_mlp_kernel(
    const unsigned short* __restrict__ nodeb,  // [50000][256] bf16
    const unsigned short* __restrict__ w1pp2,  // repacked W1 (see prep)
    const int* __restrict__ src,
    const int* __restrict__ dst,
    const float* __restrict__ b1,
    const float* __restrict__ w2,   // [512][2] fp32
    float* __restrict__ out) {      // [E][2] fp32, pre-init with b2
  // hi: [0,32K), hj: [32K,64K). unit (e,u): addr = e*512 + ((u ^ (e&7))<<4), u = step*4+quad
  __shared__ char smem[65536];

  const int tid = threadIdx.x;
  const int wid = tid >> 6;        // 0..7 -> 32-col slice
  const int lane = tid & 63;
  const int quad = lane >> 4;
  const int l16 = lane & 15;
  const int bx = blockIdx.x;
  // XCD swizzle
  const int xc = bx & 7;
  const int n_half = (bx >> 3) & 1;           // 0..1 (256-col halves)
  const int m_idx = (bx >> 4) * 8 + xc;       // 0..4095 (64-edge tiles)
  const int row0 = m_idx * 64;
  const int n0 = n_half * 256 + wid * 32;

  const char* nodeB = (const char*)nodeb;
  const char* w1B = (const char*)w1pp2;

  // ---- B register-load offsets: (s*4+quad)*8192 + (n0+l16)*16 (+ step*131072, nt*256) ----
  unsigned bOff[4];
#pragma unroll
  for (int s = 0; s < 4; ++s)
    bOff[s] = (unsigned)((s * 4 + quad) * 8192 + (n0 + l16) * 16);
  const char* w1s = w1B;

  f32x4 acc[4][2];
#pragma unroll
  for (int mt = 0; mt < 4; ++mt)
#pragma unroll
    for (int nt = 0; nt < 2; ++nt)
      acc[mt][nt] = (f32x4){0.f, 0.f, 0.f, 0.f};

  // ---- prologue: stage hi/hj once (coalesced full-row gathers, 2 per thread per call) ----
  {
    const int eh = tid >> 5;          // 0..15
    const int wsl = tid & 31;
#pragma unroll
    for (int c = 0; c < 4; ++c) {
      int e = c * 16 + eh;
      unsigned uo = (unsigned)((wsl ^ (e & 7)) << 4);
      unsigned so = ((unsigned)src[row0 + e] << 9) + uo;
      unsigned dofs = ((unsigned)dst[row0 + e] << 9) + uo;
      async_gather16(nodeB + so, smem + c * 8192 + wid * 1024);
      async_gather16(nodeB + dofs, smem + 32768 + c * 8192 + wid * 1024);
    }
  }
  __syncthreads();  // the ONLY barrier

  const unsigned aBase = (unsigned)(l16 * 512);  // + mt*16*512
  const unsigned aXor = (unsigned)(l16 & 7);
#pragma unroll 1
  for (int step = 0; step < 8; ++step) {
    // B(t) loads: 8 dwordx4, L1/L2-resident, fine-grained vmcnt by compiler
    V16 bf[4][2];
#pragma unroll
    for (int s = 0; s < 4; ++s)
#pragma unroll
      for (int nt = 0; nt < 2; ++nt)
        bf[s][nt].u = *(const uint4*)(w1s + bOff[s] + nt * 256);
    const unsigned sw = (((unsigned)(step * 4 + quad) ^ aXor) << 4);
    // per-mt JIT: load A frags, MFMA s=0,1, build, MFMA s=2,3 (keeps live regs low)
#pragma unroll
    for (int mt = 0; mt < 4; ++mt) {
      V16 hi, hj;
      unsigned ao = (unsigned)(mt * 8192) + aBase + sw;
      hi.u = *(const uint4*)(smem + ao);
      hj.u = *(const uint4*)(smem + 32768 + ao);
#pragma unroll
      for (int nt = 0; nt < 2; ++nt)
        acc[mt][nt] = __builtin_amdgcn_mfma_f32_16x16x32_bf16(hi.h, bf[0][nt].h, acc[mt][nt], 0, 0, 0);
#pragma unroll
      for (int nt = 0; nt < 2; ++nt)
        acc[mt][nt] = __builtin_amdgcn_mfma_f32_16x16x32_bf16(hj.h, bf[1][nt].h, acc[mt][nt], 0, 0, 0);
      const unsigned hw[4] = {hi.u.x, hi.u.y, hi.u.z, hi.u.w};
      const unsigned jw[4] = {hj.u.x, hj.u.y, hj.u.z, hj.u.w};
      unsigned d[4], pr[4];
#pragma unroll
      for (int w = 0; w < 4; ++w) {
        float i0 = bflo(hw[w]), i1 = bfhi(hw[w]);
        float j0 = bflo(jw[w]), j1 = bfhi(jw[w]);
        d[w] = perm_pack(i0 - j0, i1 - j1) & 0x7fff7fffu;
        pr[w] = perm_pack(i0 * j0, i1 * j1);
      }
      V16 a2, a3;
      a2.u = make_uint4(d[0], d[1], d[2], d[3]);
      a3.u = make_uint4(pr[0], pr[1], pr[2], pr[3]);
#pragma unroll
      for (int nt = 0; nt < 2; ++nt)
        acc[mt][nt] = __builtin_amdgcn_mfma_f32_16x16x32_bf16(a2.h, bf[2][nt].h, acc[mt][nt], 0, 0, 0);
#pragma unroll
      for (int nt = 0; nt < 2; ++nt)
        acc[mt][nt] = __builtin_amdgcn_mfma_f32_16x16x32_bf16(a3.h, bf[3][nt].h, acc[mt][nt], 0, 0, 0);
    }
    w1s += 131072;
  }

  // ---- epilogue: bias + ReLU + W2, 16-lane shuffle reduce, atomic out ----
#pragma unroll
  for (int mt = 0; mt < 4; ++mt) {
    float pc0[4] = {0.f, 0.f, 0.f, 0.f};
    float pc1[4] = {0.f, 0.f, 0.f, 0.f};
#pragma unroll
    for (int nt = 0; nt < 2; ++nt) {
      int gc = n0 + nt * 16 + l16;
      float b1v = b1[gc];
      float w20 = w2[gc * 2 + 0];
      float w21 = w2[gc * 2 + 1];
#pragma unroll
      for (int r = 0; r < 4; ++r) {
        float v = fmaxf(acc[mt][nt][r] + b1v, 0.f);
        pc0[r] = fmaf(v, w20, pc0[r]);
        pc1[r] = fmaf(v, w21, pc1[r]);
      }
    }
#pragma unroll
    for (int r = 0; r < 4; ++r) {
      float s0 = pc0[r], s1 = pc1[r];
#pragma unroll
      for (int off = 1; off < 16; off <<= 1) {
        s0 += __shfl_xor(s0, off);
        s1 += __shfl_xor(s1, off);
      }
      int e = row0 + mt * 16 + quad * 4 + r;  // C/D: row = quad*4 + r
      if (l16 == 0) unsafeAtomicAdd(&out[(size_t)e * 2 + 0], s0);
      if (l16 == 1) unsafeAtomicAdd(&out[(size_t)e * 2 + 1], s1);
    }
  }
}

extern "C" void kernel_launch(void* const* d_in, const int* in_sizes, int n_in,
                              void* d_out, int out_size, void* d_ws, size_t ws_size,
                              hipStream_t stream) {
  const float* node = (const float*)d_in[0];
  const int* src = (const int*)d_in[1];
  const int* dst = (const int*)d_in[2];
  const float* W1 = (const float*)d_in[3];
  const float* b1 = (const float*)d_in[4];
  const float* W2 = (const float*)d_in[5];
  const float* b2 = (const float*)d_in[6];
  float* out = (float*)d_out;

  unsigned short* nodeb = (unsigned short*)d_ws;                      // 25,600,000 B
  unsigned short* w1pp2 = (unsigned short*)((char*)d_ws + 25600000);  // 1,048,576 B

  cvt_node_kernel<<<6250, 256, 0, stream>>>(node, nodeb);
  prep_w1pp2_kernel<<<256, 256, 0, stream>>>(W1, w1pp2);
  init_out_kernel<<<1024, 256, 0, stream>>>(out, b2);
  // 4096 m-tiles (64 edges) x 2 n-halves (256 cols), 512 threads
  edge_mlp_kernel<<<8192, 512, 0, stream>>>(nodeb, w1pp2, src, dst, b1, W2, out);
}